// Round 10
// baseline (36.170 us; speedup 1.0000x reference)
//
#include <hip/hip_runtime.h>
#include <cmath>

#ifndef M_PI
#define M_PI 3.14159265358979323846
#endif

constexpr int T_LEN    = 320000;
constexpr int ROW_VECS = T_LEN / 4;               // 80000 float4 per row
constexpr int B_ROWS   = 64;
constexpr int CHUNK    = 32;                      // samples per lane
constexpr int VPT      = CHUNK / 4;               // 8 float4 per chunk
constexpr int NCHUNK   = T_LEN / CHUNK;           // 10000 chunks per row
constexpr int WCH      = 64;                      // chunks per wave (1 per lane)
constexpr int WAVES_PB = 2;                       // waves per block (128 thr)
constexpr int HALO     = 3;                       // halo chunks per wave
constexpr int WAVE_VECS = (HALO + WCH) * VPT;     // 536 vecs = 8576 B per wave
constexpr int BLK_CH   = WAVES_PB * WCH;          // 128 chunks per block

// Vector-granularity XOR swizzle (16B units), bijective per 8-vector group.
__device__ __forceinline__ int swzv(int V) { return V ^ ((V >> 3) & 7); }

__device__ __forceinline__ float4 shfl_up4(float4 v, int d) {
  float4 r;
  r.x = __shfl_up(v.x, d); r.y = __shfl_up(v.y, d);
  r.z = __shfl_up(v.z, d); r.w = __shfl_up(v.w, d);
  return r;
}
__device__ __forceinline__ float4 bcast4(float4 v, int l) {
  float4 r;
  r.x = __shfl(v.x, l); r.y = __shfl(v.y, l);
  r.z = __shfl(v.z, l); r.w = __shfl(v.w, l);
  return r;
}

// Barrier-free: each wave stages/computes/stores its own private LDS region.
// Wave-internal ds_write->ds_read ordering is enforced by lgkmcnt (compiler-
// inserted: same LDS object, may-alias). No __syncthreads anywhere.
__global__ __launch_bounds__(128, 4) void biquad_wave_kernel(
    const float* __restrict__ x, float* __restrict__ y,
    float b0, float b1, float b2, float a1, float a2,
    float q30, float p30, float q31, float p31) {
  const int b    = blockIdx.x;
  const int row  = blockIdx.y;
  const int t    = threadIdx.x;
  const int w    = t >> 6;
  const int lane = t & 63;

  const int CW = (b * WAVES_PB + w) * WCH;        // wave's first chunk
  const int wb = w * WAVE_VECS;                   // wave's LDS base (vecs)

  const float4* xr4 = reinterpret_cast<const float4*>(x + (size_t)row * T_LEN);
  float4*       yr4 = reinterpret_cast<float4*>(y + (size_t)row * T_LEN);

  __shared__ float4 tile[WAVES_PB * WAVE_VECS];   // 17152 B

  // ---- Stage [CW*8-24, CW*8+512) : batched loads -> regs -> ds_write_b128.
  {
    const float4 z4 = make_float4(0.f, 0.f, 0.f, 0.f);
    const int gbase = CW * VPT - HALO * VPT;
    float4 val[9];
#pragma unroll
    for (int j = 0; j < 9; ++j) {
      int v = j * 64 + lane;
      int g = gbase + v;
      val[j] = (v < WAVE_VECS && g >= 0 && g < ROW_VECS) ? xr4[g] : z4;
    }
#pragma unroll
    for (int j = 0; j < 9; ++j) {
      int v = j * 64 + lane;
      if (v < WAVE_VECS) tile[wb + swzv(v)] = val[j];
    }
  }

  auto stepf = [&](float xn, float& X1, float& X2, float& Y1, float& Y2) -> float {
    float tt = fmaf(b2, X2, fmaf(b1, X1, b0 * xn));
    float u  = fmaf(-a2, Y2, tt);
    float yn = fmaf(-a1, Y1, u);
    X2 = X1; X1 = xn;
    Y2 = Y1; Y1 = yn;
    return yn;
  };

  // ---- Halo: lanes 0..2 run zero-IC over halo chunks (region offsets 0..23).
  // For CW==0 the halo is zero-filled -> zero states -> exact initial rest.
  float4 H = make_float4(0.f, 0.f, 0.f, 0.f);
  if (lane < HALO) {
    const int hvb = lane * VPT;
    float hx1 = 0.f, hx2 = 0.f, hy1 = 0.f, hy2 = 0.f, hxl1 = 0.f, hxl2 = 0.f;
#pragma unroll
    for (int k = 0; k < VPT; ++k) {
      float4 hv = tile[wb + swzv(hvb + k)];
      stepf(hv.x, hx1, hx2, hy1, hy2); stepf(hv.y, hx1, hx2, hy1, hy2);
      stepf(hv.z, hx1, hx2, hy1, hy2); stepf(hv.w, hx1, hx2, hy1, hy2);
      if (k == VPT - 1) { hxl1 = hv.w; hxl2 = hv.z; }
    }
    H = make_float4(hy1, hy2, hxl1, hxl2);
  }

  // ---- Zero-IC pass over own chunk (region offset (3+lane)*8).
  float4 m[VPT];
  const int mvb = (HALO + lane) * VPT;
#pragma unroll
  for (int k = 0; k < VPT; ++k) m[k] = tile[wb + swzv(mvb + k)];
  {
    float xl1 = m[VPT - 1].w, xl2 = m[VPT - 1].z;
    float x1 = 0.f, x2 = 0.f, y1 = 0.f, y2 = 0.f;
#pragma unroll
    for (int k = 0; k < VPT; ++k) {
      float4 v = m[k];
      m[k] = make_float4(stepf(v.x, x1, x2, y1, y2), stepf(v.y, x1, x2, y1, y2),
                         stepf(v.z, x1, x2, y1, y2), stepf(v.w, x1, x2, y1, y2));
    }

    // ---- State combine via wave shuffles (exact same math as R8/R9).
    float4 Sst = make_float4(y1, y2, xl1, xl2);
    float4 up1 = shfl_up4(Sst, 1);
    float4 up2 = shfl_up4(Sst, 2);
    float4 up3 = shfl_up4(Sst, 3);
    float4 H0 = bcast4(H, 0), H1 = bcast4(H, 1), H2 = bcast4(H, 2);
    float4 sm1 = (lane == 0) ? H2 : up1;
    float4 sm2 = (lane == 0) ? H1 : ((lane == 1) ? H2 : up2);
    float4 sm3 = (lane == 0) ? H0 : ((lane == 1) ? H1 : ((lane == 2) ? H2 : up3));

    // Level A: corrected end-state of chunk-2 (seeds from chunk-3, raw z).
    float cA0 = fmaf(b1, sm3.z, fmaf(b2, sm3.w, fmaf(-a1, sm3.x, -a2 * sm3.y)));
    float cA1 = fmaf(-a1, cA0, fmaf(b2, sm3.z, -a2 * sm3.x));
    float yA1 = fmaf(q31, cA0, fmaf(p31, cA1, sm2.x));
    float yA2 = fmaf(q30, cA0, fmaf(p30, cA1, sm2.y));
    // Level B: corrected end-state of chunk-1.
    float cB0 = fmaf(b1, sm2.z, fmaf(b2, sm2.w, fmaf(-a1, yA1, -a2 * yA2)));
    float cB1 = fmaf(-a1, cB0, fmaf(b2, sm2.z, -a2 * yA1));
    float yB1 = fmaf(q31, cB0, fmaf(p31, cB1, sm1.x));
    float yB2 = fmaf(q30, cB0, fmaf(p30, cB1, sm1.y));
    // Final seeds for own chunk.
    float c0 = fmaf(b1, sm1.z, fmaf(b2, sm1.w, fmaf(-a1, yB1, -a2 * yB2)));
    float c1 = fmaf(-a1, c0, fmaf(b2, sm1.z, -a2 * yB1));
    // Apply correction chain (register-only).
    float cm2, cm1;
    {
      m[0].x += c0; m[0].y += c1;
      float c2 = fmaf(-a1, c1, -a2 * c0); m[0].z += c2;
      float c3 = fmaf(-a1, c2, -a2 * c1); m[0].w += c3;
      cm2 = c2; cm1 = c3;
    }
#pragma unroll
    for (int k = 1; k < VPT; ++k) {
      float ca = fmaf(-a1, cm1, -a2 * cm2); m[k].x += ca;
      float cb = fmaf(-a1, ca, -a2 * cm1);  m[k].y += cb;
      float cc = fmaf(-a1, cb, -a2 * ca);   m[k].z += cc;
      float cd = fmaf(-a1, cc, -a2 * cb);   m[k].w += cd;
      cm2 = cc; cm1 = cd;
    }
  }

  // ---- Writeback to own region (transpose via LDS), then coalesced store.
#pragma unroll
  for (int k = 0; k < VPT; ++k) tile[wb + swzv(mvb + k)] = m[k];

  {
    float4 o[8];
#pragma unroll
    for (int j = 0; j < 8; ++j)
      o[j] = tile[wb + swzv(HALO * VPT + j * 64 + lane)];
#pragma unroll
    for (int j = 0; j < 8; ++j) {
      int ov = CW * VPT + j * 64 + lane;
      if (ov < ROW_VECS) yr4[ov] = o[j];
    }
  }
}

extern "C" void kernel_launch(void* const* d_in, const int* in_sizes, int n_in,
                              void* d_out, int out_size, void* d_ws, size_t ws_size,
                              hipStream_t stream) {
  const float* x = (const float*)d_in[0];
  float*       y = (float*)d_out;

  const double sample_rate = 16000.0, cutoff = 7500.0, Q = 0.707;
  double w0    = 2.0 * M_PI * cutoff / sample_rate;
  double alpha = sin(w0) / (2.0 * Q);
  double cw    = cos(w0);
  double a0    = 1.0 + alpha;
  double b0d = ((1.0 - cw) * 0.5) / a0;
  double b1d = (1.0 - cw) / a0;
  double a1d = (-2.0 * cw) / a0;
  double a2d = (1.0 - alpha) / a0;

  // Homogeneous propagators: c_n = q_n*c_0 + p_n*c_1.
  double qm2 = 1.0, pm2 = 0.0, qm1 = 0.0, pm1 = 1.0;
  double q30 = 0, p30 = 0, q31 = 0, p31 = 0;
  for (int n = 2; n < CHUNK; ++n) {
    double qn = -a1d * qm1 - a2d * qm2;
    double pn = -a1d * pm1 - a2d * pm2;
    qm2 = qm1; pm2 = pm1; qm1 = qn; pm1 = pn;
    if (n == 30) { q30 = qn; p30 = pn; }
    if (n == 31) { q31 = qn; p31 = pn; }
  }

  dim3 block(128);
  dim3 grid((NCHUNK + BLK_CH - 1) / BLK_CH, B_ROWS);  // 79 x 64
  hipLaunchKernelGGL(biquad_wave_kernel, grid, block, 0, stream,
                     x, y, (float)b0d, (float)b1d, (float)b0d, (float)a1d, (float)a2d,
                     (float)q30, (float)p30, (float)q31, (float)p31);
}

// Round 11
// 30.508 us; speedup vs baseline: 1.1856x; 1.1856x over previous
//
#include <hip/hip_runtime.h>
#include <cmath>

#ifndef M_PI
#define M_PI 3.14159265358979323846
#endif

constexpr int T_LEN    = 320000;
constexpr int ROW_VECS = T_LEN / 4;               // 80000 float4 per row
constexpr int B_ROWS   = 64;
constexpr int CHUNK    = 32;                      // samples per thread
constexpr int VPT      = CHUNK / 4;               // 8 float4 per chunk
constexpr int NCHUNK   = T_LEN / CHUNK;           // 10000 chunks per row
constexpr int BLK_CHUNKS = 128;                   // chunks per block
constexpr int BLK_SPAN   = BLK_CHUNKS * CHUNK;    // 4096 samples per block
constexpr int HALO       = 3;                     // halo chunks (state combine)
constexpr int HALO_VECS  = HALO * VPT;            // 24
constexpr int TILE_VECS  = HALO_VECS + BLK_CHUNKS * VPT;  // 1048 vecs = 16.8 KB

// Vector-granularity XOR swizzle (16B units). INVOLUTION, bijective within
// each aligned 8-vector (128B) group -> pre-swizzling the global source
// address keeps wave loads inside the same 128B segments (coalesced), per
// rule #21: linear LDS dest + inverse-swz source + swz on read.
__device__ __forceinline__ int swzv(int V) { return V ^ ((V >> 3) & 7); }

typedef const __attribute__((address_space(1))) void glb_void;
typedef __attribute__((address_space(3))) void lds_void;

__global__ __launch_bounds__(256, 8) void biquad_gll_kernel(
    const float* __restrict__ x, float* __restrict__ y,
    float b0, float b1, float b2, float a1, float a2,
    float q30, float p30, float q31, float p31) {
  const int b    = blockIdx.x;
  const int row  = blockIdx.y;
  const int t    = threadIdx.x;
  const int wave = t >> 6;
  const int lane = t & 63;

  const int S       = b * BLK_SPAN;
  const int nchunks = min(BLK_CHUNKS, (T_LEN - S) / CHUNK);  // 128, or 16 (tail)
  const int nvecs   = nchunks * VPT;
  const int ntot    = HALO_VECS + nvecs;

  const float4* xr4 = reinterpret_cast<const float4*>(x + (size_t)row * T_LEN);
  float*        yr  = y + (size_t)row * T_LEN;

  __shared__ float4 tile[TILE_VECS];
  __shared__ float4 st[HALO + BLK_CHUNKS];   // (y1, y2, xlast1, xlast2)

  // ---- Phase 1: direct HBM->LDS staging. LDS slot s receives logical vec
  // swzv(s) (involution), i.e. global addr is pre-inverse-swizzled per lane;
  // LDS dest is the wave-uniform base + lane*16 that the HW requires.
  {
    const int gofs = S / 4 - HALO_VECS;   // global vec offset of slot 0
    for (int r = wave; r * 64 < ntot; r += 4) {
      int s  = r * 64 + lane;
      int gv = gofs + swzv(s);
      if (s < ntot && gv >= 0) {
        __builtin_amdgcn_global_load_lds((glb_void*)(xr4 + gv),
                                         (lds_void*)(tile + r * 64), 16, 0, 0);
      }
    }
    // Block 0: halo = zeros (exact rest state). Slots [0,24) hold the halo.
    if (b == 0 && t < HALO_VECS) tile[t] = make_float4(0.f, 0.f, 0.f, 0.f);
  }
  __syncthreads();   // drains vmcnt (gload_lds) + lgkmcnt (zero-fill)

  auto stepf = [&](float xn, float& X1, float& X2, float& Y1, float& Y2) -> float {
    float tt = fmaf(b2, X2, fmaf(b1, X1, b0 * xn));
    float u  = fmaf(-a2, Y2, tt);
    float yn = fmaf(-a1, Y1, u);
    X2 = X1; X1 = xn;
    Y2 = Y1; Y1 = yn;
    return yn;
  };

  // ---- Phase 2a: halo chunks' zero-IC end states (threads 0..2 only).
  if (t < HALO) {
    float4 h[VPT];
#pragma unroll
    for (int k = 0; k < VPT; ++k) h[k] = tile[swzv(t * VPT + k)];
    float hxl1 = h[VPT - 1].w, hxl2 = h[VPT - 1].z;
    float hx1 = 0.f, hx2 = 0.f, hy1 = 0.f, hy2 = 0.f;
#pragma unroll
    for (int k = 0; k < VPT; ++k) {
      stepf(h[k].x, hx1, hx2, hy1, hy2); stepf(h[k].y, hx1, hx2, hy1, hy2);
      stepf(h[k].z, hx1, hx2, hy1, hy2); stepf(h[k].w, hx1, hx2, hy1, hy2);
    }
    st[t] = make_float4(hy1, hy2, hxl1, hxl2);
  }

  // ---- Phase 2b: zero-IC pass over own chunk.
  const bool active = (t < nchunks);
  float4 m[VPT];
  const int vb = HALO_VECS + t * VPT;
  if (active) {
#pragma unroll
    for (int k = 0; k < VPT; ++k) m[k] = tile[swzv(vb + k)];
    float xl1 = m[VPT - 1].w, xl2 = m[VPT - 1].z;
    float x1 = 0.f, x2 = 0.f, y1 = 0.f, y2 = 0.f;
#pragma unroll
    for (int k = 0; k < VPT; ++k) {
      float4 v = m[k];
      m[k] = make_float4(stepf(v.x, x1, x2, y1, y2), stepf(v.y, x1, x2, y1, y2),
                         stepf(v.z, x1, x2, y1, y2), stepf(v.w, x1, x2, y1, y2));
    }
    st[HALO + t] = make_float4(y1, y2, xl1, xl2);
  }
  __syncthreads();

  // ---- Phase 3: 2-level state combine + correction chain (R8 math, verified).
  if (active) {
    const int i = HALO + t;
    float4 sm3 = st[i - 3], sm2 = st[i - 2], sm1 = st[i - 1];
    // Level A: corrected end-state of chunk t-2 (seeds from t-3, raw z).
    float cA0 = fmaf(b1, sm3.z, fmaf(b2, sm3.w, fmaf(-a1, sm3.x, -a2 * sm3.y)));
    float cA1 = fmaf(-a1, cA0, fmaf(b2, sm3.z, -a2 * sm3.x));
    float yA1 = fmaf(q31, cA0, fmaf(p31, cA1, sm2.x));
    float yA2 = fmaf(q30, cA0, fmaf(p30, cA1, sm2.y));
    // Level B: corrected end-state of chunk t-1.
    float cB0 = fmaf(b1, sm2.z, fmaf(b2, sm2.w, fmaf(-a1, yA1, -a2 * yA2)));
    float cB1 = fmaf(-a1, cB0, fmaf(b2, sm2.z, -a2 * yA1));
    float yB1 = fmaf(q31, cB0, fmaf(p31, cB1, sm1.x));
    float yB2 = fmaf(q30, cB0, fmaf(p30, cB1, sm1.y));
    // Final seeds for own chunk.
    float c0 = fmaf(b1, sm1.z, fmaf(b2, sm1.w, fmaf(-a1, yB1, -a2 * yB2)));
    float c1 = fmaf(-a1, c0, fmaf(b2, sm1.z, -a2 * yB1));
    // Apply correction chain (register-only).
    float cm2, cm1;
    {
      m[0].x += c0; m[0].y += c1;
      float c2 = fmaf(-a1, c1, -a2 * c0); m[0].z += c2;
      float c3 = fmaf(-a1, c2, -a2 * c1); m[0].w += c3;
      cm2 = c2; cm1 = c3;
    }
#pragma unroll
    for (int k = 1; k < VPT; ++k) {
      float ca = fmaf(-a1, cm1, -a2 * cm2); m[k].x += ca;
      float cb = fmaf(-a1, ca, -a2 * cm1);  m[k].y += cb;
      float cc = fmaf(-a1, cb, -a2 * ca);   m[k].z += cc;
      float cd = fmaf(-a1, cc, -a2 * cb);   m[k].w += cd;
      cm2 = cc; cm1 = cd;
    }
    // Own region is only read by this thread in phase 2 -> safe to overwrite.
#pragma unroll
    for (int k = 0; k < VPT; ++k) tile[swzv(vb + k)] = m[k];
  }
  __syncthreads();

  // ---- Phase 4: coalesced float4 store via swizzled ds_read_b128.
  {
    float4* dst = reinterpret_cast<float4*>(yr + S);
#pragma unroll
    for (int j = 0; j < 4; ++j) {
      int i = t + 256 * j;
      if (i < nvecs) dst[i] = tile[swzv(HALO_VECS + i)];
    }
  }
}

extern "C" void kernel_launch(void* const* d_in, const int* in_sizes, int n_in,
                              void* d_out, int out_size, void* d_ws, size_t ws_size,
                              hipStream_t stream) {
  const float* x = (const float*)d_in[0];
  float*       y = (float*)d_out;

  const double sample_rate = 16000.0, cutoff = 7500.0, Q = 0.707;
  double w0    = 2.0 * M_PI * cutoff / sample_rate;
  double alpha = sin(w0) / (2.0 * Q);
  double cw    = cos(w0);
  double a0    = 1.0 + alpha;
  double b0d = ((1.0 - cw) * 0.5) / a0;
  double b1d = (1.0 - cw) / a0;
  double a1d = (-2.0 * cw) / a0;
  double a2d = (1.0 - alpha) / a0;

  // Homogeneous propagators: c_n = q_n*c_0 + p_n*c_1.
  double qm2 = 1.0, pm2 = 0.0, qm1 = 0.0, pm1 = 1.0;
  double q30 = 0, p30 = 0, q31 = 0, p31 = 0;
  for (int n = 2; n < CHUNK; ++n) {
    double qn = -a1d * qm1 - a2d * qm2;
    double pn = -a1d * pm1 - a2d * pm2;
    qm2 = qm1; pm2 = pm1; qm1 = qn; pm1 = pn;
    if (n == 30) { q30 = qn; p30 = pn; }
    if (n == 31) { q31 = qn; p31 = pn; }
  }

  dim3 block(256);
  dim3 grid((NCHUNK + BLK_CHUNKS - 1) / BLK_CHUNKS, B_ROWS);  // 79 x 64
  hipLaunchKernelGGL(biquad_gll_kernel, grid, block, 0, stream,
                     x, y, (float)b0d, (float)b1d, (float)b0d, (float)a1d, (float)a2d,
                     (float)q30, (float)p30, (float)q31, (float)p31);
}